// Round 8
// baseline (556.479 us; speedup 1.0000x reference)
//
#include <hip/hip_runtime.h>
#include <math.h>

#define B_SZ    1024
#define IN_DIM  512
#define OUT_DIM 512
#define EMB_DIM 64
#define KQ      64

#define BM 64
#define BN 32
#define BK 16
#define KSPLIT 4
#define KCHUNK (IN_DIM / KSPLIT)   // 128
#define NT (KCHUNK / BK)           // 8 K-tiles per block

// ---------------------------------------------------------------------------
// Kernel A: coef[b] = softmax(W2 @ tanh(W1 @ concat(emb_a, emb_c) + b1))
// One wave per sample; lane j owns h[j]. Also zeroes out[] row s (needed by
// the split-K atomicAdd in kernel B; stream order guarantees completion).
// ---------------------------------------------------------------------------
__global__ __launch_bounds__(64) void coef_kernel(
    const int*   __restrict__ idx_a,
    const int*   __restrict__ idx_c,
    const float* __restrict__ emb_a,
    const float* __restrict__ emb_c,
    const float* __restrict__ W1,
    const float* __restrict__ b1,
    const float* __restrict__ W2,
    float4*      __restrict__ coef_out,
    float*       __restrict__ out)      // [B, OUT] -- zeroed here
{
    const int s = blockIdx.x;
    const int j = threadIdx.x;  // 0..63

    float4 z = make_float4(0.f, 0.f, 0.f, 0.f);
    float4* orow = (float4*)(out + (long)s * OUT_DIM);
    orow[j]       = z;
    orow[j + 64]  = z;

    const int ia = idx_a[s];
    const int ic = idx_c[s];

    const float4* ea  = (const float4*)(emb_a + (long)ia * EMB_DIM);
    const float4* ec  = (const float4*)(emb_c + (long)ic * EMB_DIM);
    const float4* w1a = (const float4*)(W1 + (long)j * (2 * EMB_DIM));
    const float4* w1c = (const float4*)(W1 + (long)j * (2 * EMB_DIM) + EMB_DIM);

    float acc = b1[j];
#pragma unroll
    for (int q = 0; q < EMB_DIM / 4; ++q) {
        float4 e = ea[q];
        float4 w = w1a[q];
        acc = fmaf(e.x, w.x, acc);
        acc = fmaf(e.y, w.y, acc);
        acc = fmaf(e.z, w.z, acc);
        acc = fmaf(e.w, w.w, acc);
    }
#pragma unroll
    for (int q = 0; q < EMB_DIM / 4; ++q) {
        float4 e = ec[q];
        float4 w = w1c[q];
        acc = fmaf(e.x, w.x, acc);
        acc = fmaf(e.y, w.y, acc);
        acc = fmaf(e.z, w.z, acc);
        acc = fmaf(e.w, w.w, acc);
    }

    float h = tanhf(acc);

    float p0 = W2[0 * KQ + j] * h;
    float p1 = W2[1 * KQ + j] * h;
    float p2 = W2[2 * KQ + j] * h;
#pragma unroll
    for (int off = 32; off > 0; off >>= 1) {
        p0 += __shfl_xor(p0, off);
        p1 += __shfl_xor(p1, off);
        p2 += __shfl_xor(p2, off);
    }

    float m  = fmaxf(p0, fmaxf(p1, p2));
    float e0 = expf(p0 - m), e1 = expf(p1 - m), e2 = expf(p2 - m);
    float inv = 1.0f / (e0 + e1 + e2);

    if (j == 0) coef_out[s] = make_float4(e0 * inv, e1 * inv, e2 * inv, 0.0f);
}

// ---------------------------------------------------------------------------
// Kernel B: split-K fused 4-channel GEMM, double-buffered LDS, vectorized
// staging, one barrier per K-tile, atomicAdd epilogue.
// R4-proven shape: 256 thr, BM=64, BN=32, BK=16, KSPLIT=4, tile 4x2x4ch.
// Grid 16 x 16 x 4 = 1024 blocks -> 4 blocks/CU -> 16 waves/CU (4/SIMD).
// Staging per thread per tile: 1 x-float4 + 1.5 w3-float4 + 0.5 b3-float4
// (w3 per-kk segment = 96 contiguous 16B-aligned floats since o0 % 32 == 0).
// ---------------------------------------------------------------------------
__global__ __launch_bounds__(256, 4) void gemm_kernel(
    const float*  __restrict__ x,    // [1024, 512]
    const float*  __restrict__ w3,   // [512*512, 3]
    const float*  __restrict__ b3,   // [512*512]
    const float4* __restrict__ coef, // [1024]
    float*        __restrict__ out)  // [1024, 512] (pre-zeroed)
{
    __shared__ float xs[2][BK][BM + 4];   // transposed x tile: xs[.][kk][m]
    __shared__ float ws[2][BK][4][BN];    // [.][kk][basis0..2, bias][o]

    const int t    = threadIdx.x;
    const int tx   = t & 15;   // cols tx*2, tx*2+1
    const int ty   = t >> 4;   // rows ty*4 .. ty*4+3
    const int row0 = blockIdx.y * BM;
    const int o0   = blockIdx.x * BN;
    const int kb   = blockIdx.z * KCHUNK;

    const float4* w3f4 = (const float4*)w3;
    const float4* b3f4 = (const float4*)b3;
    const int w3base = (o0 * 3) >> 2;   // float4 offset of o0 within a k-row
    const int b3base = o0 >> 2;

    // constant per-thread staging coordinates
    const int sm   = t >> 2;          // x row 0..63
    const int skb  = (t & 3) * 4;     // x k-sub 0,4,8,12
    const int seg0 = t / 24,       q0 = t % 24;        // w3 f4 idx t
    const int idx1 = t + 256;
    const int seg1 = idx1 / 24,    q1 = idx1 % 24;     // w3 f4 idx t+256 (t<128)
    const int bkk  = (t - 128) >> 3, bq = (t - 128) & 7; // b3 (t>=128)

    float4 rx, rw0, rw1rb;  // rw1rb: w3 part 2 for t<128, b3 for t>=128

    float acc[4][2][4];
#pragma unroll
    for (int i = 0; i < 4; ++i)
#pragma unroll
        for (int j = 0; j < 2; ++j)
#pragma unroll
            for (int c = 0; c < 4; ++c) acc[i][j][c] = 0.0f;

#define ISSUE(K0)                                                          \
    do {                                                                   \
        rx  = *(const float4*)(x + (long)(row0 + sm) * IN_DIM + (K0) + skb); \
        rw0 = w3f4[(long)((K0) + seg0) * 384 + w3base + q0];               \
        if (t < 128) {                                                     \
            rw1rb = w3f4[(long)((K0) + seg1) * 384 + w3base + q1];         \
        } else {                                                           \
            rw1rb = b3f4[(long)((K0) + bkk) * 128 + b3base + bq];          \
        }                                                                  \
    } while (0)

#define STORE(BUF)                                                         \
    do {                                                                   \
        xs[BUF][skb + 0][sm] = rx.x;                                       \
        xs[BUF][skb + 1][sm] = rx.y;                                       \
        xs[BUF][skb + 2][sm] = rx.z;                                       \
        xs[BUF][skb + 3][sm] = rx.w;                                       \
        const float* p0v = (const float*)&rw0;                             \
        _Pragma("unroll")                                                  \
        for (int j = 0; j < 4; ++j) {                                      \
            int off = q0 * 4 + j;                                          \
            ws[BUF][seg0][off % 3][off / 3] = p0v[j];                      \
        }                                                                  \
        const float* p1v = (const float*)&rw1rb;                           \
        if (t < 128) {                                                     \
            _Pragma("unroll")                                              \
            for (int j = 0; j < 4; ++j) {                                  \
                int off = q1 * 4 + j;                                      \
                ws[BUF][seg1][off % 3][off / 3] = p1v[j];                  \
            }                                                              \
        } else {                                                           \
            *(float4*)&ws[BUF][bkk][3][bq * 4] = rw1rb;                    \
        }                                                                  \
    } while (0)

    ISSUE(kb);
    STORE(0);

    for (int tt = 0; tt < NT; ++tt) {
        const bool more = (tt + 1 < NT);
        if (more) ISSUE(kb + (tt + 1) * BK);   // prefetch next tile into regs

        __syncthreads();                       // lds[tt&1] writes visible

        const int buf = tt & 1;
#pragma unroll
        for (int kk = 0; kk < BK; ++kk) {
            const float4 av = *(const float4*)&xs[buf][kk][ty * 4];
            const float a[4] = {av.x, av.y, av.z, av.w};
#pragma unroll
            for (int c = 0; c < 4; ++c) {
                const float2 wv = *(const float2*)&ws[buf][kk][c][tx * 2];
#pragma unroll
                for (int i = 0; i < 4; ++i) {
                    acc[i][0][c] = fmaf(a[i], wv.x, acc[i][0][c]);
                    acc[i][1][c] = fmaf(a[i], wv.y, acc[i][1][c]);
                }
            }
        }

        if (more) STORE((tt + 1) & 1);         // safe: other buffer; readers
                                               // of it finished before the
                                               // barrier at top of this iter
    }

    // epilogue: combine channels with softmax coefs, atomicAdd the partial
#pragma unroll
    for (int i = 0; i < 4; ++i) {
        const int r = row0 + ty * 4 + i;
        const float4 cf = coef[r];
#pragma unroll
        for (int j = 0; j < 2; ++j) {
            float v = acc[i][j][3];
            v = fmaf(acc[i][j][0], cf.x, v);
            v = fmaf(acc[i][j][1], cf.y, v);
            v = fmaf(acc[i][j][2], cf.z, v);
            atomicAdd(&out[(long)r * OUT_DIM + o0 + tx * 2 + j], v);
        }
    }
#undef ISSUE
#undef STORE
}

// ---------------------------------------------------------------------------
extern "C" void kernel_launch(void* const* d_in, const int* in_sizes, int n_in,
                              void* d_out, int out_size, void* d_ws, size_t ws_size,
                              hipStream_t stream) {
    const float* x     = (const float*)d_in[0];
    const int*   idx_a = (const int*)  d_in[1];
    const int*   idx_c = (const int*)  d_in[2];
    const float* emb_a = (const float*)d_in[3];
    const float* emb_c = (const float*)d_in[4];
    const float* W1    = (const float*)d_in[5];
    const float* b1    = (const float*)d_in[6];
    const float* W2    = (const float*)d_in[7];
    const float* W3    = (const float*)d_in[8];
    const float* b3    = (const float*)d_in[9];
    float*       out   = (float*)d_out;

    float4* coef = (float4*)d_ws;

    coef_kernel<<<B_SZ, 64, 0, stream>>>(idx_a, idx_c, emb_a, emb_c, W1, b1, W2,
                                         coef, out);

    dim3 grid(OUT_DIM / BN, B_SZ / BM, KSPLIT);  // 16 x 16 x 4 = 1024 blocks
    gemm_kernel<<<grid, 256, 0, stream>>>(x, W3, b3, coef, out);
}

// Round 9
// 127.555 us; speedup vs baseline: 4.3627x; 4.3627x over previous
//
#include <hip/hip_runtime.h>
#include <math.h>

#define B_SZ    1024
#define IN_DIM  512
#define OUT_DIM 512
#define EMB_DIM 64
#define KQ      64

#define BM 64
#define BN 32
#define BK 16
#define KSPLIT 8
#define KCHUNK (IN_DIM / KSPLIT)   // 64 -> 4 K-tiles per block

// ---------------------------------------------------------------------------
// Kernel A: coef[b] = softmax(W2 @ tanh(W1 @ concat(emb_a, emb_c) + b1))
// One wave per sample; lane j owns h[j]. Also zeroes out[] row s (needed by
// the split-K atomicAdd in kernel B; stream order guarantees completion).
// ---------------------------------------------------------------------------
__global__ __launch_bounds__(64) void coef_kernel(
    const int*   __restrict__ idx_a,
    const int*   __restrict__ idx_c,
    const float* __restrict__ emb_a,
    const float* __restrict__ emb_c,
    const float* __restrict__ W1,
    const float* __restrict__ b1,
    const float* __restrict__ W2,
    float4*      __restrict__ coef_out,
    float*       __restrict__ out)      // [B, OUT] -- zeroed here
{
    const int s = blockIdx.x;
    const int j = threadIdx.x;  // 0..63

    float4 z = make_float4(0.f, 0.f, 0.f, 0.f);
    float4* orow = (float4*)(out + (long)s * OUT_DIM);
    orow[j]       = z;
    orow[j + 64]  = z;

    const int ia = idx_a[s];
    const int ic = idx_c[s];

    const float4* ea  = (const float4*)(emb_a + (long)ia * EMB_DIM);
    const float4* ec  = (const float4*)(emb_c + (long)ic * EMB_DIM);
    const float4* w1a = (const float4*)(W1 + (long)j * (2 * EMB_DIM));
    const float4* w1c = (const float4*)(W1 + (long)j * (2 * EMB_DIM) + EMB_DIM);

    float acc = b1[j];
#pragma unroll
    for (int q = 0; q < EMB_DIM / 4; ++q) {
        float4 e = ea[q];
        float4 w = w1a[q];
        acc = fmaf(e.x, w.x, acc);
        acc = fmaf(e.y, w.y, acc);
        acc = fmaf(e.z, w.z, acc);
        acc = fmaf(e.w, w.w, acc);
    }
#pragma unroll
    for (int q = 0; q < EMB_DIM / 4; ++q) {
        float4 e = ec[q];
        float4 w = w1c[q];
        acc = fmaf(e.x, w.x, acc);
        acc = fmaf(e.y, w.y, acc);
        acc = fmaf(e.z, w.z, acc);
        acc = fmaf(e.w, w.w, acc);
    }

    float h = tanhf(acc);

    float p0 = W2[0 * KQ + j] * h;
    float p1 = W2[1 * KQ + j] * h;
    float p2 = W2[2 * KQ + j] * h;
#pragma unroll
    for (int off = 32; off > 0; off >>= 1) {
        p0 += __shfl_xor(p0, off);
        p1 += __shfl_xor(p1, off);
        p2 += __shfl_xor(p2, off);
    }

    float m  = fmaxf(p0, fmaxf(p1, p2));
    float e0 = expf(p0 - m), e1 = expf(p1 - m), e2 = expf(p2 - m);
    float inv = 1.0f / (e0 + e1 + e2);

    if (j == 0) coef_out[s] = make_float4(e0 * inv, e1 * inv, e2 * inv, 0.0f);
}

// ---------------------------------------------------------------------------
// Kernel B: split-K fused 4-channel GEMM + epilogue combine + atomicAdd.
// EXACT R4 structure (measured 40.8us @ KSPLIT=4): 256 thr, BM=64, BN=32,
// BK=16, single-buffer LDS, 2 barriers/tile, thread tile 4x2x4ch.
// ONLY change vs R4: KSPLIT 4 -> 8.
// Grid 16 x 16 x 8 = 2048 blocks -> 8 blocks/CU -> 32 waves/CU (8/SIMD).
// Cross-block phase overlap hides the stage-phase VMEM latency (m114).
// ---------------------------------------------------------------------------
__global__ __launch_bounds__(256, 8) void gemm_kernel(
    const float*  __restrict__ x,    // [1024, 512]
    const float*  __restrict__ w3,   // [512*512, 3]
    const float*  __restrict__ b3,   // [512*512]
    const float4* __restrict__ coef, // [1024]
    float*        __restrict__ out)  // [1024, 512] (pre-zeroed)
{
    __shared__ float xs[BK][BM + 4];   // transposed x tile: xs[kk][m]
    __shared__ float ws[BK][4][BN];    // [kk][basis0..2, bias][o]

    const int t    = threadIdx.x;
    const int tx   = t & 15;   // cols tx*2, tx*2+1
    const int ty   = t >> 4;   // rows ty*4 .. ty*4+3
    const int row0 = blockIdx.y * BM;
    const int o0   = blockIdx.x * BN;
    const int kb   = blockIdx.z * KCHUNK;

    float acc[4][2][4];
#pragma unroll
    for (int i = 0; i < 4; ++i)
#pragma unroll
        for (int j = 0; j < 2; ++j)
#pragma unroll
            for (int c = 0; c < 4; ++c) acc[i][j][c] = 0.0f;

    for (int k0 = kb; k0 < kb + KCHUNK; k0 += BK) {
        // ---- stage x tile (transposed): one float4 per thread ----
        {
            const int m   = t >> 2;          // 0..63
            const int kkb = (t & 3) * 4;     // 0,4,8,12
            float4 v = *(const float4*)(x + (long)(row0 + m) * IN_DIM + k0 + kkb);
            xs[kkb + 0][m] = v.x;
            xs[kkb + 1][m] = v.y;
            xs[kkb + 2][m] = v.z;
            xs[kkb + 3][m] = v.w;
        }
        // ---- stage W tile: 512 (kk,o) positions, 2 per thread, 4 ch each ----
#pragma unroll
        for (int r = 0; r < 2; ++r) {
            const int pos = t + r * 256;
            const int kk  = pos >> 5;        // 0..15
            const int o   = pos & 31;        // 0..31
            const long g  = (long)(k0 + kk) * OUT_DIM + (o0 + o);
            const float* wp = w3 + g * 3;
            ws[kk][0][o] = wp[0];
            ws[kk][1][o] = wp[1];
            ws[kk][2][o] = wp[2];
            ws[kk][3][o] = b3[g];
        }
        __syncthreads();

        // ---- compute ----
#pragma unroll
        for (int kk = 0; kk < BK; ++kk) {
            const float4 av = *(const float4*)&xs[kk][ty * 4];
            const float a[4] = {av.x, av.y, av.z, av.w};
#pragma unroll
            for (int c = 0; c < 4; ++c) {
                const float2 wv = *(const float2*)&ws[kk][c][tx * 2];
#pragma unroll
                for (int i = 0; i < 4; ++i) {
                    acc[i][0][c] = fmaf(a[i], wv.x, acc[i][0][c]);
                    acc[i][1][c] = fmaf(a[i], wv.y, acc[i][1][c]);
                }
            }
        }
        __syncthreads();
    }

    // epilogue: combine channels with softmax coefs, atomicAdd the partial
#pragma unroll
    for (int i = 0; i < 4; ++i) {
        const int r = row0 + ty * 4 + i;
        const float4 cf = coef[r];
#pragma unroll
        for (int j = 0; j < 2; ++j) {
            float v = acc[i][j][3];
            v = fmaf(acc[i][j][0], cf.x, v);
            v = fmaf(acc[i][j][1], cf.y, v);
            v = fmaf(acc[i][j][2], cf.z, v);
            atomicAdd(&out[(long)r * OUT_DIM + o0 + tx * 2 + j], v);
        }
    }
}

// ---------------------------------------------------------------------------
extern "C" void kernel_launch(void* const* d_in, const int* in_sizes, int n_in,
                              void* d_out, int out_size, void* d_ws, size_t ws_size,
                              hipStream_t stream) {
    const float* x     = (const float*)d_in[0];
    const int*   idx_a = (const int*)  d_in[1];
    const int*   idx_c = (const int*)  d_in[2];
    const float* emb_a = (const float*)d_in[3];
    const float* emb_c = (const float*)d_in[4];
    const float* W1    = (const float*)d_in[5];
    const float* b1    = (const float*)d_in[6];
    const float* W2    = (const float*)d_in[7];
    const float* W3    = (const float*)d_in[8];
    const float* b3    = (const float*)d_in[9];
    float*       out   = (float*)d_out;

    float4* coef = (float4*)d_ws;

    coef_kernel<<<B_SZ, 64, 0, stream>>>(idx_a, idx_c, emb_a, emb_c, W1, b1, W2,
                                         coef, out);

    dim3 grid(OUT_DIM / BN, B_SZ / BM, KSPLIT);  // 16 x 16 x 8 = 2048 blocks
    gemm_kernel<<<grid, 256, 0, stream>>>(x, W3, b3, coef, out);
}